// Round 4
// baseline (179.108 us; speedup 1.0000x reference)
//
#include <hip/hip_runtime.h>
#include <math.h>

// Problem constants (fixed by the reference setup)
#define BATCH      16384
#define CLIP       50
#define DIM        64
#define PAD_IDX    100000
#define NITER      13   // ceil(CLIP/4): 4 friends per wave-iteration
#define PF         6    // gather prefetch depth (6*4=24 VGPR for fe buffer)

// One wave per batch element.
// Lane mapping: sub = lane>>4 (friend slot within group of 4), li = lane&15
// (dim chunk: each lane owns dims [li*4, li*4+4) as a float4).
//
// R3: rolling 6-deep gather pipeline at <=64 VGPR so we keep BOTH
// 8 waves/SIMD occupancy AND ~48 outstanding gathers per SIMD.
// Friend ids come in via wave-uniform scalar loads (s_load), keeping the
// vector-memory pipe exclusively for the 256B embedding-row gathers.
__global__ __launch_bounds__(256, 8) void gmf_kernel(
    const int*   __restrict__ user_indices,        // [B]
    const int*   __restrict__ item_indices,        // [B]
    const int*   __restrict__ user_friend_indices, // [NU, CLIP]
    const float* __restrict__ emb_user,            // [PAD_IDX+1, D] (pad row = 0)
    const float* __restrict__ emb_item,            // [NI, D]
    const float* __restrict__ affine_w,            // [D]
    const float* __restrict__ affine_b,            // [1]
    float*       __restrict__ out)                 // [B] ratings ++ [B*CLIP] gates
{
    const int wave = (blockIdx.x * blockDim.x + threadIdx.x) >> 6;
    const int lane = threadIdx.x & 63;
    if (wave >= BATCH) return;

    const int b   = wave;
    const int sub = lane >> 4;   // friend slot in group of 4
    const int li  = lane & 15;   // dim-chunk index

    const int u  = user_indices[b];   // wave-uniform
    const int it = item_indices[b];   // wave-uniform
    const float bias = affine_b[0];

    const float4 ie = *(const float4*)(emb_item + (size_t)it * DIM + li * 4);
    const float4 w4 = *(const float4*)(affine_w + li * 4);
    float4 v;
    v.x = ie.x * w4.x; v.y = ie.y * w4.y; v.z = ie.z * w4.z; v.w = ie.w * w4.w;

    const int* fi_row = user_friend_indices + (size_t)u * CLIP;

    // Friend ids: wave-uniform addresses -> scalar loads, select by sub.
    int ids[NITER];
    #pragma unroll
    for (int i = 0; i < 12; ++i) {
        const int4 q = *(const int4*)(fi_row + 4 * i);   // uniform -> s_load
        ids[i] = (sub == 0) ? q.x : (sub == 1) ? q.y : (sub == 2) ? q.z : q.w;
    }
    {   // slots 48,49 real; 50,51 out of range -> PAD (zero row, not counted)
        const int2 q = *(const int2*)(fi_row + 48);      // uniform -> s_load
        ids[12] = (sub == 0) ? q.x : (sub == 1) ? q.y : PAD_IDX;
    }

    // Prime the pipeline: PF gathers in flight.
    float4 fe[PF];
    #pragma unroll
    for (int i = 0; i < PF; ++i)
        fe[i] = *(const float4*)(emb_user + (size_t)ids[i] * DIM + li * 4);

    float4 acc = make_float4(0.f, 0.f, 0.f, 0.f);
    float gkeep = 0.f;   // lane (li,sub) keeps gate of friend c = 4*li+sub
    float cl    = 0.f;   // per-lane real-friend count over its 13 slots

    #pragma unroll
    for (int i = 0; i < NITER; ++i) {
        const float4 cur = fe[i % PF];
        if (i + PF < NITER)   // refill the slot we just drained
            fe[i % PF] = *(const float4*)(emb_user + (size_t)ids[i + PF] * DIM + li * 4);

        // partial dot over this lane's 4 dims, then 16-lane butterfly
        // (reduces all 4 friends-in-flight simultaneously).
        float p = cur.x * v.x + cur.y * v.y + cur.z * v.z + cur.w * v.w;
        p += __shfl_xor(p, 1, 64);
        p += __shfl_xor(p, 2, 64);
        p += __shfl_xor(p, 4, 64);
        p += __shfl_xor(p, 8, 64);

        const float g = 1.0f / (1.0f + __expf(-(p + bias)));

        acc.x += cur.x * g; acc.y += cur.y * g;
        acc.z += cur.z * g; acc.w += cur.w * g;

        if (li == i) gkeep = g;
        cl += (ids[i] != PAD_IDX) ? 1.0f : 0.0f;
    }

    // Friend count: lanes sharing `sub` are identical; sum the 4 sub-groups.
    float cntf = cl;
    cntf += __shfl_xor(cntf, 16, 64);
    cntf += __shfl_xor(cntf, 32, 64);

    // logits: full-wave reduce of acc·v (covers dim and friend-group sums).
    float q = acc.x * v.x + acc.y * v.y + acc.z * v.z + acc.w * v.w;
    q += __shfl_xor(q, 1, 64);
    q += __shfl_xor(q, 2, 64);
    q += __shfl_xor(q, 4, 64);
    q += __shfl_xor(q, 8, 64);
    q += __shfl_xor(q, 16, 64);
    q += __shfl_xor(q, 32, 64);

    const float rating = 1.0f / (1.0f + __expf(-(q / cntf + bias)));

    if (lane == 0)
        out[b] = rating;

    // Gate store: lane (li,sub) holds gate of friend c = 4*li+sub.
    const int c = 4 * li + sub;
    if (c < CLIP)
        out[BATCH + (size_t)b * CLIP + c] = gkeep;  // one 200B scattered store
}

extern "C" void kernel_launch(void* const* d_in, const int* in_sizes, int n_in,
                              void* d_out, int out_size, void* d_ws, size_t ws_size,
                              hipStream_t stream) {
    const int*   user_indices        = (const int*)  d_in[0];
    const int*   item_indices        = (const int*)  d_in[1];
    const int*   user_friend_indices = (const int*)  d_in[2];
    const float* emb_user            = (const float*)d_in[3];
    const float* emb_item            = (const float*)d_in[4];
    const float* affine_w            = (const float*)d_in[5];
    const float* affine_b            = (const float*)d_in[6];
    float*       out                 = (float*)d_out;

    const int threads = 256;
    const int blocks  = (BATCH * 64) / threads; // 4096
    gmf_kernel<<<blocks, threads, 0, stream>>>(
        user_indices, item_indices, user_friend_indices,
        emb_user, emb_item, affine_w, affine_b, out);
}

// Round 5
// 167.301 us; speedup vs baseline: 1.0706x; 1.0706x over previous
//
#include <hip/hip_runtime.h>
#include <math.h>

// Problem constants (fixed by the reference setup)
#define BATCH      16384
#define CLIP       50
#define DIM        64
#define PAD_IDX    100000
#define NITER      13   // ceil(CLIP/4): 4 friends per wave-iteration

// One wave per batch element.
// Lane mapping: sub = lane>>4 (friend slot within group of 4), li = lane&15
// (dim chunk: each lane owns dims [li*4, li*4+4) as a float4).
//
// R4: R2's full-depth gather batch (13 float4 loads in flight = max MLP per
// wave) + __launch_bounds__(256,6) for 6 waves/SIMD (~85 VGPR cap — fits the
// ~70-reg live set WITHOUT spilling; R3's (256,8)=64-reg cap spilled to
// scratch: WRITE_SIZE 3.3->122 MB, kernel 38->87 us).
__global__ __launch_bounds__(256, 6) void gmf_kernel(
    const int*   __restrict__ user_indices,        // [B]
    const int*   __restrict__ item_indices,        // [B]
    const int*   __restrict__ user_friend_indices, // [NU, CLIP]
    const float* __restrict__ emb_user,            // [PAD_IDX+1, D] (pad row = 0)
    const float* __restrict__ emb_item,            // [NI, D]
    const float* __restrict__ affine_w,            // [D]
    const float* __restrict__ affine_b,            // [1]
    float*       __restrict__ out)                 // [B] ratings ++ [B*CLIP] gates
{
    const int wave = (blockIdx.x * blockDim.x + threadIdx.x) >> 6;
    const int lane = threadIdx.x & 63;
    if (wave >= BATCH) return;

    const int b   = wave;
    const int sub = lane >> 4;   // friend slot in group of 4
    const int li  = lane & 15;   // dim-chunk index

    const int u  = user_indices[b];   // wave-uniform
    const int it = item_indices[b];   // wave-uniform

    const int* fi_row = user_friend_indices + (size_t)u * CLIP;

    // Friend ids: wave-uniform addresses -> scalar loads, select by sub.
    // (slots 50,51 out of range -> PAD: zero embedding row, not counted)
    int ids[NITER];
    #pragma unroll
    for (int i = 0; i < 12; ++i) {
        const int4 q = *(const int4*)(fi_row + 4 * i);   // uniform -> s_load
        ids[i] = (sub == 0) ? q.x : (sub == 1) ? q.y : (sub == 2) ? q.z : q.w;
    }
    {
        const int2 q = *(const int2*)(fi_row + 48);      // uniform -> s_load
        ids[12] = (sub == 0) ? q.x : (sub == 1) ? q.y : PAD_IDX;
    }

    // Issue ALL 13 row gathers back-to-back (pad row of emb_user is zero).
    // Address regs die at issue; only the 52 dest VGPRs stay live.
    float4 fe[NITER];
    #pragma unroll
    for (int i = 0; i < NITER; ++i)
        fe[i] = *(const float4*)(emb_user + (size_t)ids[i] * DIM + li * 4);

    // v = ie * w for this lane's 4 dims (loaded after gathers are in flight;
    // ie/w4 die immediately to keep the live set small).
    const float bias = affine_b[0];
    const float4 ie = *(const float4*)(emb_item + (size_t)it * DIM + li * 4);
    const float4 w4 = *(const float4*)(affine_w + li * 4);
    float4 v;
    v.x = ie.x * w4.x; v.y = ie.y * w4.y; v.z = ie.z * w4.z; v.w = ie.w * w4.w;

    float4 acc = make_float4(0.f, 0.f, 0.f, 0.f);
    float gkeep = 0.f;   // lane (li,sub) keeps gate of friend c = 4*li+sub
    float cl    = 0.f;   // per-lane real-friend count over its 13 slots

    #pragma unroll
    for (int i = 0; i < NITER; ++i) {
        // partial dot over this lane's 4 dims, then 16-lane butterfly
        // (reduces all 4 friends-in-flight simultaneously).
        float p = fe[i].x * v.x + fe[i].y * v.y + fe[i].z * v.z + fe[i].w * v.w;
        p += __shfl_xor(p, 1, 64);
        p += __shfl_xor(p, 2, 64);
        p += __shfl_xor(p, 4, 64);
        p += __shfl_xor(p, 8, 64);

        const float g = 1.0f / (1.0f + __expf(-(p + bias)));

        acc.x += fe[i].x * g; acc.y += fe[i].y * g;
        acc.z += fe[i].z * g; acc.w += fe[i].w * g;

        if (li == i) gkeep = g;
        cl += (ids[i] != PAD_IDX) ? 1.0f : 0.0f;
    }

    // Friend count: lanes sharing `sub` are identical; sum the 4 sub-groups.
    float cntf = cl;
    cntf += __shfl_xor(cntf, 16, 64);
    cntf += __shfl_xor(cntf, 32, 64);

    // logits: full-wave reduce of acc·v (covers dim and friend-group sums).
    float q = acc.x * v.x + acc.y * v.y + acc.z * v.z + acc.w * v.w;
    q += __shfl_xor(q, 1, 64);
    q += __shfl_xor(q, 2, 64);
    q += __shfl_xor(q, 4, 64);
    q += __shfl_xor(q, 8, 64);
    q += __shfl_xor(q, 16, 64);
    q += __shfl_xor(q, 32, 64);

    const float rating = 1.0f / (1.0f + __expf(-(q / cntf + bias)));

    if (lane == 0)
        out[b] = rating;

    // Gate store: lane (li,sub) holds gate of friend c = 4*li+sub.
    const int c = 4 * li + sub;
    if (c < CLIP)
        out[BATCH + (size_t)b * CLIP + c] = gkeep;  // one 200B scattered store
}

extern "C" void kernel_launch(void* const* d_in, const int* in_sizes, int n_in,
                              void* d_out, int out_size, void* d_ws, size_t ws_size,
                              hipStream_t stream) {
    const int*   user_indices        = (const int*)  d_in[0];
    const int*   item_indices        = (const int*)  d_in[1];
    const int*   user_friend_indices = (const int*)  d_in[2];
    const float* emb_user            = (const float*)d_in[3];
    const float* emb_item            = (const float*)d_in[4];
    const float* affine_w            = (const float*)d_in[5];
    const float* affine_b            = (const float*)d_in[6];
    float*       out                 = (float*)d_out;

    const int threads = 256;
    const int blocks  = (BATCH * 64) / threads; // 4096
    gmf_kernel<<<blocks, threads, 0, stream>>>(
        user_indices, item_indices, user_friend_indices,
        emb_user, emb_item, affine_w, affine_b, out);
}

// Round 6
// 127.397 us; speedup vs baseline: 1.4059x; 1.3132x over previous
//
#include <hip/hip_runtime.h>
#include <math.h>

// Problem constants (fixed by the reference setup)
#define BATCH    16384
#define CLIP     50
#define DIM      64
#define PAD_IDX  100000
#define HALF     25   // friends handled per wave (element split across 2 waves)
#define NIT      7    // ceil(HALF/4): 4 friends per wave-iteration

// TWO waves per batch element (25 friends each), one block = 2 elements.
// Lane mapping inside a wave: sub = lane>>4 (friend slot within group of 4),
// li = lane&15 (dim chunk: lane owns dims [li*4, li*4+4) as a float4).
//
// R5: R2's proven no-spill "batch all gathers into registers" structure, but
// fe[] depth 7 instead of 13 so the natural live set fits ~64 VGPR -> 8
// waves/SIMD WITHOUT __launch_bounds__ min-waves coercion (R3/R4 showed
// waves-per-eu caps make the scheduler spill to scratch: WRITE_SIZE 89-122MB).
// Cross-wave combine: 2 floats/wave through LDS + one __syncthreads.
__global__ __launch_bounds__(256) void gmf_kernel(
    const int*   __restrict__ user_indices,        // [B]
    const int*   __restrict__ item_indices,        // [B]
    const int*   __restrict__ user_friend_indices, // [NU, CLIP]
    const float* __restrict__ emb_user,            // [PAD_IDX+1, D] (pad row = 0)
    const float* __restrict__ emb_item,            // [NI, D]
    const float* __restrict__ affine_w,            // [D]
    const float* __restrict__ affine_b,            // [1]
    float*       __restrict__ out)                 // [B] ratings ++ [B*CLIP] gates
{
    const int tid  = threadIdx.x;
    const int lane = tid & 63;
    const int wv   = (tid >> 6) & 1;   // wave within element (0: friends 0-24, 1: 25-49)
    const int eb   = tid >> 7;         // element within block (0,1)
    const int b    = blockIdx.x * 2 + eb;

    const int sub = lane >> 4;   // friend slot in group of 4
    const int li  = lane & 15;   // dim-chunk index

    const int u  = user_indices[b];   // wave-uniform
    const int it = item_indices[b];   // wave-uniform

    const int* fi_row = user_friend_indices + (size_t)u * CLIP + wv * HALF;

    // Phase 1+2: load friend ids, fold the real-friend count in immediately
    // (so ids die at gather-issue), and batch ALL 7 row gathers back-to-back.
    // Pad slots (local c >= 25) and PAD ids hit emb_user's all-zero row.
    float  cl = 0.f;      // per-lane real-friend count over its 7 slots
    float4 fe[NIT];
    #pragma unroll
    for (int i = 0; i < NIT; ++i) {
        const int c = 4 * i + sub;                       // local slot 0..27
        const int f = (c < HALF) ? fi_row[c] : PAD_IDX;
        cl += (f != PAD_IDX) ? 1.f : 0.f;
        fe[i] = *(const float4*)(emb_user + (size_t)f * DIM + li * 4);
    }

    // v = ie * w for this lane's 4 dims (after gathers are in flight).
    const float bias = affine_b[0];
    const float4 ie = *(const float4*)(emb_item + (size_t)it * DIM + li * 4);
    const float4 w4 = *(const float4*)(affine_w + li * 4);
    float4 v;
    v.x = ie.x * w4.x; v.y = ie.y * w4.y; v.z = ie.z * w4.z; v.w = ie.w * w4.w;

    // Phase 3: per-friend gate + gated accumulation.
    float4 acc = make_float4(0.f, 0.f, 0.f, 0.f);
    float gkeep = 0.f;   // lane (li,sub) keeps gate of local slot 4*li+sub

    #pragma unroll
    for (int i = 0; i < NIT; ++i) {
        // partial dot over this lane's 4 dims, then 16-lane butterfly
        // (reduces all 4 friends-in-flight simultaneously).
        float p = fe[i].x * v.x + fe[i].y * v.y + fe[i].z * v.z + fe[i].w * v.w;
        p += __shfl_xor(p, 1, 64);
        p += __shfl_xor(p, 2, 64);
        p += __shfl_xor(p, 4, 64);
        p += __shfl_xor(p, 8, 64);

        const float g = 1.0f / (1.0f + __expf(-(p + bias)));

        acc.x += fe[i].x * g; acc.y += fe[i].y * g;
        acc.z += fe[i].z * g; acc.w += fe[i].w * g;

        if (li == i) gkeep = g;
    }

    // Wave-partial friend count: lanes sharing `sub` are identical copies;
    // sum the 4 sub-groups.
    float cntw = cl;
    cntw += __shfl_xor(cntw, 16, 64);
    cntw += __shfl_xor(cntw, 32, 64);

    // Wave-partial logit: full-wave reduce of acc·v (dims + friend-groups).
    float q = acc.x * v.x + acc.y * v.y + acc.z * v.z + acc.w * v.w;
    q += __shfl_xor(q, 1, 64);
    q += __shfl_xor(q, 2, 64);
    q += __shfl_xor(q, 4, 64);
    q += __shfl_xor(q, 8, 64);
    q += __shfl_xor(q, 16, 64);
    q += __shfl_xor(q, 32, 64);

    // Cross-wave combine (2 waves per element): 2 floats per wave via LDS.
    __shared__ float red[2][2][2];   // [element][wave][q, cnt]
    if (lane == 0) {
        red[eb][wv][0] = q;
        red[eb][wv][1] = cntw;
    }
    __syncthreads();

    if (wv == 0 && lane == 0) {
        const float qt = red[eb][0][0] + red[eb][1][0];
        const float ct = red[eb][0][1] + red[eb][1][1];
        out[b] = 1.0f / (1.0f + __expf(-(qt / ct + bias)));
    }

    // Gate store: lane (li,sub) holds gate of local slot c = 4*li+sub.
    const int c = 4 * li + sub;
    if (c < HALF)
        out[BATCH + (size_t)b * CLIP + wv * HALF + c] = gkeep;
}

extern "C" void kernel_launch(void* const* d_in, const int* in_sizes, int n_in,
                              void* d_out, int out_size, void* d_ws, size_t ws_size,
                              hipStream_t stream) {
    const int*   user_indices        = (const int*)  d_in[0];
    const int*   item_indices        = (const int*)  d_in[1];
    const int*   user_friend_indices = (const int*)  d_in[2];
    const float* emb_user            = (const float*)d_in[3];
    const float* emb_item            = (const float*)d_in[4];
    const float* affine_w            = (const float*)d_in[5];
    const float* affine_b            = (const float*)d_in[6];
    float*       out                 = (float*)d_out;

    // 2 waves per element, 2 elements per 256-thread block.
    const int threads = 256;
    const int blocks  = BATCH / 2; // 8192
    gmf_kernel<<<blocks, threads, 0, stream>>>(
        user_indices, item_indices, user_friend_indices,
        emb_user, emb_item, affine_w, affine_b, out);
}